// Round 18
// baseline (52.450 us; speedup 1.0000x reference)
//
#include <hip/hip_runtime.h>
#include <stdint.h>

// Two-kernel 3x3 neighborhood-attention.
//  K1 coef8_kernel: coef7's shape (block=row, wave=16ch quarter, lane=quad,
//    coalesced float4, shfl margins, S-collapsed sumsq) + T14 double-buffered
//    REGISTER staging: two named 8xfloat4 stage sets; burst i+1's loads issue
//    before consume(i) -> L2/L3 latency overlaps compute instead of serializing.
//  K2 apply_kernel: float4 streaming out = exp(-(nbr-ref)^2)*sum_k coef_k*nbr_k.
// Shapes: [b=2, c=64, h=256, w=256] fp32.

constexpr int C = 64, H = 256, W = 256, HW = H * W;
constexpr int B = 2, PIX = B * HW;

// ---------------- K1: coefficient kernel ----------------
__global__ __launch_bounds__(256, 2) void coef8_kernel(const float* __restrict__ nbr,
                                                       const float* __restrict__ ref,
                                                       float* __restrict__ coef) {
  __shared__ float part[19][4][W];    // 77,824 B

  const int tid  = threadIdx.x;
  const int lane = tid & 63;          // quad index; x0 = 4*lane
  const int wv   = tid >> 6;          // channel quarter 0..3
  const int x0   = lane * 4;

  // XCD band swizzle: 512 blocks, bijective
  const int by = ((blockIdx.x & 7) << 6) | (blockIdx.x >> 3);
  const int b  = by >> 8;
  const int y  = by & 255;
  const int ym = (y == 0)     ? 1     : y - 1;   // jnp reflect
  const int yp = (y == H - 1) ? H - 2 : y + 1;

  const float* nbase = nbr + (size_t)b * C * HW;
  const float* rrow  = ref + (size_t)b * C * HW + y * W;
  const int oM = ym * W, oC = y * W, oP = yp * W;
  const int c0 = wv * 16;

  float dt[4][9], s2[3][6], sr[4];
#pragma unroll
  for (int e = 0; e < 4; ++e) {
    sr[e] = 0.f;
#pragma unroll
    for (int k = 0; k < 9; ++k) dt[e][k] = 0.f;
  }
#pragma unroll
  for (int r = 0; r < 3; ++r)
#pragma unroll
    for (int i = 0; i < 6; ++i) s2[r][i] = 0.f;

  // two named stage sets (burst = 2 channels x {3 nbr rows + ref})
  float4 A0m, A0c, A0p, Af0, A1m, A1c, A1p, Af1;
  float4 B0m, B0c, B0p, Bf0, B1m, B1c, B1p, Bf1;

  auto consume2 = [&](const float4 v0m, const float4 v0c, const float4 v0p, const float4 rf0,
                      const float4 v1m, const float4 v1c, const float4 v1p, const float4 rf1) {
#pragma unroll
    for (int u = 0; u < 2; ++u) {
      const float4 rf = u ? rf1 : rf0;
      const float4 rows[3] = {u ? v1m : v0m, u ? v1c : v0c, u ? v1p : v0p};
      const float rfe[4] = {rf.x, rf.y, rf.z, rf.w};
      sr[0] = fmaf(rfe[0], rfe[0], sr[0]);
      sr[1] = fmaf(rfe[1], rfe[1], sr[1]);
      sr[2] = fmaf(rfe[2], rfe[2], sr[2]);
      sr[3] = fmaf(rfe[3], rfe[3], sr[3]);
#pragma unroll
      for (int r = 0; r < 3; ++r) {
        const float4 v = rows[r];
        float L = __shfl(v.w, lane - 1);
        float R = __shfl(v.x, lane + 1);
        if (lane == 0)  L = v.y;      // reflect: x=-1 -> 1
        if (lane == 63) R = v.z;      // reflect: x=256 -> 254
        const float win[6] = {L, v.x, v.y, v.z, v.w, R};
#pragma unroll
        for (int i = 0; i < 6; ++i) s2[r][i] = fmaf(win[i], win[i], s2[r][i]);
        const int kb = r * 3;
#pragma unroll
        for (int e = 0; e < 4; ++e)
#pragma unroll
          for (int cx = 0; cx < 3; ++cx)
            dt[e][kb + cx] = fmaf(rfe[e], win[e + cx], dt[e][kb + cx]);
      }
    }
  };

#define LOAD_SET(S, burst)                                                       \
  {                                                                              \
    const float* p0_ = nbase + (size_t)(c0 + (burst) * 2 + 0) * HW;              \
    const float* p1_ = nbase + (size_t)(c0 + (burst) * 2 + 1) * HW;              \
    S##0m = *(const float4*)(p0_ + oM + x0);                                     \
    S##0c = *(const float4*)(p0_ + oC + x0);                                     \
    S##0p = *(const float4*)(p0_ + oP + x0);                                     \
    S##f0 = *(const float4*)(rrow + (size_t)(c0 + (burst) * 2 + 0) * HW + x0);   \
    S##1m = *(const float4*)(p1_ + oM + x0);                                     \
    S##1c = *(const float4*)(p1_ + oC + x0);                                     \
    S##1p = *(const float4*)(p1_ + oP + x0);                                     \
    S##f1 = *(const float4*)(rrow + (size_t)(c0 + (burst) * 2 + 1) * HW + x0);   \
  }

  // software pipeline over 8 bursts: loads of burst i+1 in flight during consume(i)
  LOAD_SET(A, 0)
#pragma unroll
  for (int i = 0; i < 8; i += 2) {
    LOAD_SET(B, i + 1)
    consume2(A0m, A0c, A0p, Af0, A1m, A1c, A1p, Af1);
    if (i + 2 < 8) LOAD_SET(A, i + 2)
    consume2(B0m, B0c, B0p, Bf0, B1m, B1c, B1p, Bf1);
  }
#undef LOAD_SET

  // ---- one-shot cross-wave reduce through LDS ----
#pragma unroll
  for (int k = 0; k < 9; ++k) {
    *(float4*)&part[k][wv][x0] = float4{dt[0][k], dt[1][k], dt[2][k], dt[3][k]};
    const int r = k / 3, cx = k % 3;   // sq[e][k] = s2[r][e+cx]
    *(float4*)&part[9 + k][wv][x0] = float4{s2[r][cx], s2[r][cx + 1], s2[r][cx + 2], s2[r][cx + 3]};
  }
  *(float4*)&part[18][wv][x0] = float4{sr[0], sr[1], sr[2], sr[3]};
  __syncthreads();

  // thread tid <-> pixel tid for softmax/store
  float td[9], tq[9];
#pragma unroll
  for (int k = 0; k < 9; ++k) {
    td[k] = part[k][0][tid] + part[k][1][tid] + part[k][2][tid] + part[k][3][tid];
    tq[k] = part[9 + k][0][tid] + part[9 + k][1][tid] + part[9 + k][2][tid] + part[9 + k][3][tid];
  }
  const float tsr = part[18][0][tid] + part[18][1][tid] + part[18][2][tid] + part[18][3][tid];

  const float invr = __frsqrt_rn(fmaxf(tsr, 1e-24f));
  float d[9], invp[9];
  float mx = -INFINITY;
#pragma unroll
  for (int k = 0; k < 9; ++k) {
    invp[k] = __frsqrt_rn(fmaxf(tq[k], 1e-24f));
    d[k]    = td[k] * invr * invp[k];
    mx      = fmaxf(mx, d[k]);
  }
  float s = 0.f;
  float cf[9];
#pragma unroll
  for (int k = 0; k < 9; ++k) {
    cf[k] = __expf(d[k] - mx);
    s += cf[k];
  }
  const float sinv = 1.0f / s;

  const int pix = by * W + tid;
#pragma unroll
  for (int k = 0; k < 9; ++k)
    coef[(size_t)k * PIX + pix] = cf[k] * sinv * invp[k];   // patch l2norm folded
}

// ---------------- K2: apply kernel (proven; XCD swizzle, grid=4096) ----------------
__global__ __launch_bounds__(256) void apply_kernel(const float* __restrict__ nbr,
                                                    const float* __restrict__ ref,
                                                    const float* __restrict__ coef,
                                                    float* __restrict__ out) {
  const int blk  = ((blockIdx.x & 7) << 9) | (blockIdx.x >> 3);  // bijective on [0,4096)
  const int gid  = blk * 256 + threadIdx.x;
  const int lane = gid & 63;
  const int x0   = lane * 4;
  const int t    = gid >> 6;
  const int y    = t & 255;
  const int u    = t >> 8;
  const int b    = u >> 5;
  const int c0   = (u & 31) * 2;

  const int ym = (y == 0)     ? 1     : y - 1;
  const int yp = (y == H - 1) ? H - 2 : y + 1;

  const float* n0  = nbr + ((size_t)b * C + c0) * HW;
  const float* n1  = n0 + HW;
  const float* r0p = ref + ((size_t)b * C + c0) * HW;
  float*       o0  = out + ((size_t)b * C + c0) * HW;

  const float4 a0 = *(const float4*)(n0 + ym * W + x0);
  const float4 a1 = *(const float4*)(n0 + y  * W + x0);
  const float4 a2 = *(const float4*)(n0 + yp * W + x0);
  const float4 b0 = *(const float4*)(n1 + ym * W + x0);
  const float4 b1 = *(const float4*)(n1 + y  * W + x0);
  const float4 b2 = *(const float4*)(n1 + yp * W + x0);
  const float4 f0 = *(const float4*)(r0p + y * W + x0);
  const float4 f1 = *(const float4*)(r0p + HW + y * W + x0);

  float La0 = __shfl(a0.w, lane - 1), Ra0 = __shfl(a0.x, lane + 1);
  float La1 = __shfl(a1.w, lane - 1), Ra1 = __shfl(a1.x, lane + 1);
  float La2 = __shfl(a2.w, lane - 1), Ra2 = __shfl(a2.x, lane + 1);
  float Lb0 = __shfl(b0.w, lane - 1), Rb0 = __shfl(b0.x, lane + 1);
  float Lb1 = __shfl(b1.w, lane - 1), Rb1 = __shfl(b1.x, lane + 1);
  float Lb2 = __shfl(b2.w, lane - 1), Rb2 = __shfl(b2.x, lane + 1);
  if (lane == 0)  { La0 = a0.y; La1 = a1.y; La2 = a2.y; Lb0 = b0.y; Lb1 = b1.y; Lb2 = b2.y; }
  if (lane == 63) { Ra0 = a0.z; Ra1 = a1.z; Ra2 = a2.z; Rb0 = b0.z; Rb1 = b1.z; Rb2 = b2.z; }

  float va[3][6] = {{La0, a0.x, a0.y, a0.z, a0.w, Ra0},
                    {La1, a1.x, a1.y, a1.z, a1.w, Ra1},
                    {La2, a2.x, a2.y, a2.z, a2.w, Ra2}};
  float vb[3][6] = {{Lb0, b0.x, b0.y, b0.z, b0.w, Rb0},
                    {Lb1, b1.x, b1.y, b1.z, b1.w, Rb1},
                    {Lb2, b2.x, b2.y, b2.z, b2.w, Rb2}};

  const int cbase = b * HW + y * W + x0;
  float aga[4] = {0.f, 0.f, 0.f, 0.f};
  float agb[4] = {0.f, 0.f, 0.f, 0.f};
#pragma unroll
  for (int k = 0; k < 9; ++k) {
    const float4 cf = *(const float4*)(coef + (size_t)k * PIX + cbase);
    const int r  = k / 3;
    const int cx = k % 3;
    const float cfe[4] = {cf.x, cf.y, cf.z, cf.w};
#pragma unroll
    for (int e = 0; e < 4; ++e) {
      aga[e] = fmaf(cfe[e], va[r][e + cx], aga[e]);
      agb[e] = fmaf(cfe[e], vb[r][e + cx], agb[e]);
    }
  }

  const float ctra[4] = {a1.x, a1.y, a1.z, a1.w};
  const float ctrb[4] = {b1.x, b1.y, b1.z, b1.w};
  const float rfa[4]  = {f0.x, f0.y, f0.z, f0.w};
  const float rfb[4]  = {f1.x, f1.y, f1.z, f1.w};
  float oae[4], obe[4];
#pragma unroll
  for (int e = 0; e < 4; ++e) {
    const float da = ctra[e] - rfa[e];
    const float db = ctrb[e] - rfb[e];
    oae[e] = aga[e] * __expf(-(da * da));
    obe[e] = agb[e] * __expf(-(db * db));
  }
  float4 oa, ob4;
  oa.x = oae[0]; oa.y = oae[1]; oa.z = oae[2]; oa.w = oae[3];
  ob4.x = obe[0]; ob4.y = obe[1]; ob4.z = obe[2]; ob4.w = obe[3];

  *(float4*)(o0 + y * W + x0) = oa;
  *(float4*)(o0 + HW + y * W + x0) = ob4;
}

// ---------------- fallback: R4 fused kernel (if ws too small) ----------------
__global__ __launch_bounds__(256) void fused_nbr_attn(const float* __restrict__ nbr,
                                                      const float* __restrict__ ref,
                                                      float* __restrict__ out) {
  const int tid  = threadIdx.x;
  const int lane = tid & 63;
  const int wv   = tid >> 6;
  const int px   = lane & 7;
  const int cg   = lane >> 3;

  const int pix = blockIdx.x * 32 + wv * 8 + px;
  const int b   = pix >> 16;
  const int p   = pix & (HW - 1);
  const int y   = p >> 8;
  const int x   = p & (W - 1);

  const int ym = (y == 0)     ? 1     : y - 1;
  const int yp = (y == H - 1) ? H - 2 : y + 1;
  const int xm = (x == 0)     ? 1     : x - 1;
  const int xp = (x == W - 1) ? W - 2 : x + 1;

  int off[9];
  off[0] = ym * W + xm; off[1] = ym * W + x; off[2] = ym * W + xp;
  off[3] = y  * W + xm; off[4] = y  * W + x; off[5] = y  * W + xp;
  off[6] = yp * W + xm; off[7] = yp * W + x; off[8] = yp * W + xp;
  const int ctr = y * W + x;

  const float* nb = nbr + ((size_t)b * C + cg * 8) * HW;
  const float* rb = ref + ((size_t)b * C + cg * 8) * HW;
  float*       ob = out + ((size_t)b * C + cg * 8) * HW;

  float v[8][9], r[8];
#pragma unroll
  for (int j = 0; j < 8; ++j) {
    r[j] = rb[j * HW + ctr];
#pragma unroll
    for (int k = 0; k < 9; ++k) v[j][k] = nb[j * HW + off[k]];
  }
  float sr = 0.f;
  float dot[9], ss[9];
#pragma unroll
  for (int k = 0; k < 9; ++k) { dot[k] = 0.f; ss[k] = 0.f; }
#pragma unroll
  for (int j = 0; j < 8; ++j) {
    sr = fmaf(r[j], r[j], sr);
#pragma unroll
    for (int k = 0; k < 9; ++k) {
      dot[k] = fmaf(r[j], v[j][k], dot[k]);
      ss[k]  = fmaf(v[j][k], v[j][k], ss[k]);
    }
  }
#pragma unroll
  for (int m = 8; m < 64; m <<= 1) {
    sr += __shfl_xor(sr, m);
#pragma unroll
    for (int k = 0; k < 9; ++k) {
      dot[k] += __shfl_xor(dot[k], m);
      ss[k]  += __shfl_xor(ss[k], m);
    }
  }
  const float invr = __frsqrt_rn(fmaxf(sr, 1e-24f));
  float d[9], invp[9];
  float mx = -INFINITY;
#pragma unroll
  for (int k = 0; k < 9; ++k) {
    invp[k] = __frsqrt_rn(fmaxf(ss[k], 1e-24f));
    d[k]    = dot[k] * invr * invp[k];
    mx      = fmaxf(mx, d[k]);
  }
  float s = 0.f;
  float coef[9];
#pragma unroll
  for (int k = 0; k < 9; ++k) {
    const float e = __expf(d[k] - mx);
    coef[k] = e;
    s += e;
  }
  const float sinv = 1.0f / s;
#pragma unroll
  for (int k = 0; k < 9; ++k) coef[k] *= sinv * invp[k];
#pragma unroll
  for (int j = 0; j < 8; ++j) {
    float a = 0.f;
#pragma unroll
    for (int k = 0; k < 9; ++k) a = fmaf(coef[k], v[j][k], a);
    const float diff = v[j][4] - r[j];
    const float wd   = __expf(-(diff * diff));
    ob[j * HW + ctr] = a * wd;
  }
}

extern "C" void kernel_launch(void* const* d_in, const int* in_sizes, int n_in,
                              void* d_out, int out_size, void* d_ws, size_t ws_size,
                              hipStream_t stream) {
  const float* nbr = (const float*)d_in[0];
  const float* ref = (const float*)d_in[1];
  float*       out = (float*)d_out;
  const size_t coef_bytes = (size_t)9 * PIX * sizeof(float);

  if (ws_size >= coef_bytes) {
    float* coef = (float*)d_ws;
    coef8_kernel<<<dim3(B * H), dim3(256), 0, stream>>>(nbr, ref, coef);     // 512 row-blocks
    apply_kernel<<<dim3(PIX / 4 * (C / 2) / 256), dim3(256), 0, stream>>>(nbr, ref, coef, out);  // 4096
  } else {
    fused_nbr_attn<<<dim3(PIX / 32), dim3(256), 0, stream>>>(nbr, ref, out);
  }
}

// Round 19
// 31.086 us; speedup vs baseline: 1.6872x; 1.6872x over previous
//
#include <hip/hip_runtime.h>
#include <stdint.h>

// Single fused 3x3 neighborhood-attention kernel.
//  Pass A (coef7 structure): block = one image row, 4 waves = 16-ch quarters,
//    lane = quad (4 px). Per channel: 3 nbr float4 + 1 ref float4 (fully
//    coalesced), x-margins via __shfl, S-collapsed sumsq accumulators.
//    Cross-wave reduce via LDS [19][4][256]; per-pixel softmax.
//  Coefs (patch-l2norm folded) parked in LDS (9x256, reusing reduce buffer).
//  Pass B (apply folded in): per wave the SAME 16 channels (L2/L3-hot
//    re-read), coefs hoisted to 9 float4 regs, out = exp(-(nbr-ref)^2) *
//    sum_k coef_k * nbr_k, coalesced float4 stores.
//  No workspace, no second launch, no coef HBM round-trip.
// Shapes: [b=2, c=64, h=256, w=256] fp32.

constexpr int C = 64, H = 256, W = 256, HW = H * W;
constexpr int B = 2;

__global__ __launch_bounds__(256, 2) void fused_kernel(const float* __restrict__ nbr,
                                                       const float* __restrict__ ref,
                                                       float* __restrict__ out) {
  __shared__ float part[19][4][W];    // 77,824 B; planes 0..8 reused for coefs

  const int tid  = threadIdx.x;
  const int lane = tid & 63;          // quad index; x0 = 4*lane
  const int wv   = tid >> 6;          // channel quarter 0..3
  const int x0   = lane * 4;

  // XCD band swizzle: 512 blocks, bijective
  const int by = ((blockIdx.x & 7) << 6) | (blockIdx.x >> 3);
  const int b  = by >> 8;
  const int y  = by & 255;
  const int ym = (y == 0)     ? 1     : y - 1;   // jnp reflect
  const int yp = (y == H - 1) ? H - 2 : y + 1;

  const float* nbase = nbr + (size_t)b * C * HW;
  const float* rrow  = ref + (size_t)b * C * HW + y * W;
  float*       obase = out + (size_t)b * C * HW + y * W;
  const int oM = ym * W, oC = y * W, oP = yp * W;
  const int c0 = wv * 16;

  // ================= Pass A: accumulate =================
  float dt[4][9], s2[3][6], sr[4];
#pragma unroll
  for (int e = 0; e < 4; ++e) {
    sr[e] = 0.f;
#pragma unroll
    for (int k = 0; k < 9; ++k) dt[e][k] = 0.f;
  }
#pragma unroll
  for (int r = 0; r < 3; ++r)
#pragma unroll
    for (int i = 0; i < 6; ++i) s2[r][i] = 0.f;

#pragma unroll 4
  for (int cc = 0; cc < 16; ++cc) {
    const float* cb = nbase + (size_t)(c0 + cc) * HW;
    const float4 am = *(const float4*)(cb + oM + x0);
    const float4 ac = *(const float4*)(cb + oC + x0);
    const float4 ap = *(const float4*)(cb + oP + x0);
    const float4 rf = *(const float4*)(rrow + (size_t)(c0 + cc) * HW + x0);
    const float rfe[4] = {rf.x, rf.y, rf.z, rf.w};
    sr[0] = fmaf(rfe[0], rfe[0], sr[0]);
    sr[1] = fmaf(rfe[1], rfe[1], sr[1]);
    sr[2] = fmaf(rfe[2], rfe[2], sr[2]);
    sr[3] = fmaf(rfe[3], rfe[3], sr[3]);
    const float4 rows[3] = {am, ac, ap};
#pragma unroll
    for (int r = 0; r < 3; ++r) {
      const float4 v = rows[r];
      float L = __shfl(v.w, lane - 1);
      float R = __shfl(v.x, lane + 1);
      if (lane == 0)  L = v.y;        // reflect: x=-1 -> 1
      if (lane == 63) R = v.z;        // reflect: x=256 -> 254
      const float win[6] = {L, v.x, v.y, v.z, v.w, R};
#pragma unroll
      for (int i = 0; i < 6; ++i) s2[r][i] = fmaf(win[i], win[i], s2[r][i]);
      const int kb = r * 3;
#pragma unroll
      for (int e = 0; e < 4; ++e)
#pragma unroll
        for (int cx = 0; cx < 3; ++cx)
          dt[e][kb + cx] = fmaf(rfe[e], win[e + cx], dt[e][kb + cx]);
    }
  }

  // ---- cross-wave reduce through LDS ----
#pragma unroll
  for (int k = 0; k < 9; ++k) {
    *(float4*)&part[k][wv][x0] = float4{dt[0][k], dt[1][k], dt[2][k], dt[3][k]};
    const int r = k / 3, cx = k % 3;   // sq[e][k] = s2[r][e+cx]
    *(float4*)&part[9 + k][wv][x0] = float4{s2[r][cx], s2[r][cx + 1], s2[r][cx + 2], s2[r][cx + 3]};
  }
  *(float4*)&part[18][wv][x0] = float4{sr[0], sr[1], sr[2], sr[3]};
  __syncthreads();

  float td[9], tq[9];
#pragma unroll
  for (int k = 0; k < 9; ++k) {
    td[k] = part[k][0][tid] + part[k][1][tid] + part[k][2][tid] + part[k][3][tid];
    tq[k] = part[9 + k][0][tid] + part[9 + k][1][tid] + part[9 + k][2][tid] + part[9 + k][3][tid];
  }
  const float tsr = part[18][0][tid] + part[18][1][tid] + part[18][2][tid] + part[18][3][tid];

  // ---- softmax (per pixel = tid) ----
  const float invr = __frsqrt_rn(fmaxf(tsr, 1e-24f));
  float d[9], invp[9];
  float mx = -INFINITY;
#pragma unroll
  for (int k = 0; k < 9; ++k) {
    invp[k] = __frsqrt_rn(fmaxf(tq[k], 1e-24f));
    d[k]    = td[k] * invr * invp[k];
    mx      = fmaxf(mx, d[k]);
  }
  float s = 0.f;
  float cfv[9];
#pragma unroll
  for (int k = 0; k < 9; ++k) {
    cfv[k] = __expf(d[k] - mx);
    s += cfv[k];
  }
  const float sinv = 1.0f / s;

  __syncthreads();   // all part[] reads done; safe to overwrite with coefs
  float* wc = &part[0][0][0];          // coefs: wc[k*256 + px]
#pragma unroll
  for (int k = 0; k < 9; ++k)
    wc[k * W + tid] = cfv[k] * sinv * invp[k];   // patch l2norm folded
  __syncthreads();

  // ================= Pass B: apply (L2/L3-hot re-read) =================
  float4 cf4[9];
#pragma unroll
  for (int k = 0; k < 9; ++k) cf4[k] = *(const float4*)&wc[k * W + x0];

#pragma unroll 2
  for (int cc = 0; cc < 16; ++cc) {
    const int c = c0 + cc;
    const float* cb = nbase + (size_t)c * HW;
    const float4 am = *(const float4*)(cb + oM + x0);
    const float4 ac = *(const float4*)(cb + oC + x0);
    const float4 ap = *(const float4*)(cb + oP + x0);
    const float4 rf = *(const float4*)(rrow + (size_t)c * HW + x0);

    float agg[4] = {0.f, 0.f, 0.f, 0.f};
    const float4 rows[3] = {am, ac, ap};
#pragma unroll
    for (int r = 0; r < 3; ++r) {
      const float4 v = rows[r];
      float L = __shfl(v.w, lane - 1);
      float R = __shfl(v.x, lane + 1);
      if (lane == 0)  L = v.y;
      if (lane == 63) R = v.z;
      const float win[6] = {L, v.x, v.y, v.z, v.w, R};
#pragma unroll
      for (int cx = 0; cx < 3; ++cx) {
        const float4 cf = cf4[r * 3 + cx];
        const float cfe[4] = {cf.x, cf.y, cf.z, cf.w};
#pragma unroll
        for (int e = 0; e < 4; ++e)
          agg[e] = fmaf(cfe[e], win[e + cx], agg[e]);
      }
    }
    const float ctr[4] = {ac.x, ac.y, ac.z, ac.w};
    const float rfe[4] = {rf.x, rf.y, rf.z, rf.w};
    float oe[4];
#pragma unroll
    for (int e = 0; e < 4; ++e) {
      const float da = ctr[e] - rfe[e];
      oe[e] = agg[e] * __expf(-(da * da));   // exp(ALPHA*(nbr-ref)^2), ALPHA=-1
    }
    float4 o4;
    o4.x = oe[0]; o4.y = oe[1]; o4.z = oe[2]; o4.w = oe[3];
    *(float4*)(obase + (size_t)c * HW + x0) = o4;
  }
}

extern "C" void kernel_launch(void* const* d_in, const int* in_sizes, int n_in,
                              void* d_out, int out_size, void* d_ws, size_t ws_size,
                              hipStream_t stream) {
  const float* nbr = (const float*)d_in[0];
  const float* ref = (const float*)d_in[1];
  float*       out = (float*)d_out;
  fused_kernel<<<dim3(B * H), dim3(256), 0, stream>>>(nbr, ref, out);   // 512 row-blocks
}

// Round 20
// 30.883 us; speedup vs baseline: 1.6983x; 1.0066x over previous
//
#include <hip/hip_runtime.h>
#include <stdint.h>

// Single fused 3x3 neighborhood-attention kernel (R18 + occupancy fix).
//  Pass A: block = one image row, 4 waves = 16-ch quarters, lane = quad.
//    Per channel: 3 nbr float4 + 1 ref float4 (fully coalesced), x-margins
//    via __shfl, S-collapsed sumsq accumulators.
//  Cross-wave reduce in TWO rounds through a [10][4][256] LDS buffer
//    (40,960 B vs R18's 77,824 B) -> 4 blocks/CU instead of 2: doubles
//    resident waves to cover L2/L3 latency (the measured 80% stall).
//  Softmax per pixel; coefs parked in LDS; Pass B = apply folded in
//    (L3-hot re-read, 9 coef float4 regs, coalesced stores).
// Shapes: [b=2, c=64, h=256, w=256] fp32.

constexpr int C = 64, H = 256, W = 256, HW = H * W;
constexpr int B = 2;

__global__ __launch_bounds__(256, 2) void fused_kernel(const float* __restrict__ nbr,
                                                       const float* __restrict__ ref,
                                                       float* __restrict__ out) {
  __shared__ float buf[10][4][W];     // 40,960 B; also reused for coefs (9KB)

  const int tid  = threadIdx.x;
  const int lane = tid & 63;          // quad index; x0 = 4*lane
  const int wv   = tid >> 6;          // channel quarter 0..3
  const int x0   = lane * 4;

  // XCD band swizzle: 512 blocks, bijective
  const int by = ((blockIdx.x & 7) << 6) | (blockIdx.x >> 3);
  const int b  = by >> 8;
  const int y  = by & 255;
  const int ym = (y == 0)     ? 1     : y - 1;   // jnp reflect
  const int yp = (y == H - 1) ? H - 2 : y + 1;

  const float* nbase = nbr + (size_t)b * C * HW;
  const float* rrow  = ref + (size_t)b * C * HW + y * W;
  float*       obase = out + (size_t)b * C * HW + y * W;
  const int oM = ym * W, oC = y * W, oP = yp * W;
  const int c0 = wv * 16;

  // ================= Pass A: accumulate =================
  float dt[4][9], s2[3][6], sr[4];
#pragma unroll
  for (int e = 0; e < 4; ++e) {
    sr[e] = 0.f;
#pragma unroll
    for (int k = 0; k < 9; ++k) dt[e][k] = 0.f;
  }
#pragma unroll
  for (int r = 0; r < 3; ++r)
#pragma unroll
    for (int i = 0; i < 6; ++i) s2[r][i] = 0.f;

#pragma unroll 4
  for (int cc = 0; cc < 16; ++cc) {
    const float* cb = nbase + (size_t)(c0 + cc) * HW;
    const float4 am = *(const float4*)(cb + oM + x0);
    const float4 ac = *(const float4*)(cb + oC + x0);
    const float4 ap = *(const float4*)(cb + oP + x0);
    const float4 rf = *(const float4*)(rrow + (size_t)(c0 + cc) * HW + x0);
    const float rfe[4] = {rf.x, rf.y, rf.z, rf.w};
    sr[0] = fmaf(rfe[0], rfe[0], sr[0]);
    sr[1] = fmaf(rfe[1], rfe[1], sr[1]);
    sr[2] = fmaf(rfe[2], rfe[2], sr[2]);
    sr[3] = fmaf(rfe[3], rfe[3], sr[3]);
    const float4 rows[3] = {am, ac, ap};
#pragma unroll
    for (int r = 0; r < 3; ++r) {
      const float4 v = rows[r];
      float L = __shfl(v.w, lane - 1);
      float R = __shfl(v.x, lane + 1);
      if (lane == 0)  L = v.y;        // reflect: x=-1 -> 1
      if (lane == 63) R = v.z;        // reflect: x=256 -> 254
      const float win[6] = {L, v.x, v.y, v.z, v.w, R};
#pragma unroll
      for (int i = 0; i < 6; ++i) s2[r][i] = fmaf(win[i], win[i], s2[r][i]);
      const int kb = r * 3;
#pragma unroll
      for (int e = 0; e < 4; ++e)
#pragma unroll
        for (int cx = 0; cx < 3; ++cx)
          dt[e][kb + cx] = fmaf(rfe[e], win[e + cx], dt[e][kb + cx]);
    }
  }

  // ---- reduce round A: dt[9] + sr through buf[10] ----
#pragma unroll
  for (int k = 0; k < 9; ++k)
    *(float4*)&buf[k][wv][x0] = float4{dt[0][k], dt[1][k], dt[2][k], dt[3][k]};
  *(float4*)&buf[9][wv][x0] = float4{sr[0], sr[1], sr[2], sr[3]};
  __syncthreads();

  float td[9];
#pragma unroll
  for (int k = 0; k < 9; ++k)
    td[k] = buf[k][0][tid] + buf[k][1][tid] + buf[k][2][tid] + buf[k][3][tid];
  const float tsr = buf[9][0][tid] + buf[9][1][tid] + buf[9][2][tid] + buf[9][3][tid];
  __syncthreads();   // all round-A reads done before round-B overwrites

  // ---- reduce round B: sq[9] (from S-collapsed s2) ----
#pragma unroll
  for (int k = 0; k < 9; ++k) {
    const int r = k / 3, cx = k % 3;   // sq[e][k] = s2[r][e+cx]
    *(float4*)&buf[k][wv][x0] = float4{s2[r][cx], s2[r][cx + 1], s2[r][cx + 2], s2[r][cx + 3]};
  }
  __syncthreads();

  float tq[9];
#pragma unroll
  for (int k = 0; k < 9; ++k)
    tq[k] = buf[k][0][tid] + buf[k][1][tid] + buf[k][2][tid] + buf[k][3][tid];

  // ---- softmax (per pixel = tid) ----
  const float invr = __frsqrt_rn(fmaxf(tsr, 1e-24f));
  float d[9], invp[9];
  float mx = -INFINITY;
#pragma unroll
  for (int k = 0; k < 9; ++k) {
    invp[k] = __frsqrt_rn(fmaxf(tq[k], 1e-24f));
    d[k]    = td[k] * invr * invp[k];
    mx      = fmaxf(mx, d[k]);
  }
  float s = 0.f;
  float cfv[9];
#pragma unroll
  for (int k = 0; k < 9; ++k) {
    cfv[k] = __expf(d[k] - mx);
    s += cfv[k];
  }
  const float sinv = 1.0f / s;

  __syncthreads();   // all round-B reads done; safe to overwrite with coefs
  float* wc = &buf[0][0][0];           // coefs: wc[k*256 + px]  (9KB)
#pragma unroll
  for (int k = 0; k < 9; ++k)
    wc[k * W + tid] = cfv[k] * sinv * invp[k];   // patch l2norm folded
  __syncthreads();

  // ================= Pass B: apply (L2/L3-hot re-read) =================
  float4 cf4[9];
#pragma unroll
  for (int k = 0; k < 9; ++k) cf4[k] = *(const float4*)&wc[k * W + x0];

#pragma unroll 2
  for (int cc = 0; cc < 16; ++cc) {
    const int c = c0 + cc;
    const float* cb = nbase + (size_t)c * HW;
    const float4 am = *(const float4*)(cb + oM + x0);
    const float4 ac = *(const float4*)(cb + oC + x0);
    const float4 ap = *(const float4*)(cb + oP + x0);
    const float4 rf = *(const float4*)(rrow + (size_t)c * HW + x0);

    float agg[4] = {0.f, 0.f, 0.f, 0.f};
    const float4 rows[3] = {am, ac, ap};
#pragma unroll
    for (int r = 0; r < 3; ++r) {
      const float4 v = rows[r];
      float L = __shfl(v.w, lane - 1);
      float R = __shfl(v.x, lane + 1);
      if (lane == 0)  L = v.y;
      if (lane == 63) R = v.z;
      const float win[6] = {L, v.x, v.y, v.z, v.w, R};
#pragma unroll
      for (int cx = 0; cx < 3; ++cx) {
        const float4 cf = cf4[r * 3 + cx];
        const float cfe[4] = {cf.x, cf.y, cf.z, cf.w};
#pragma unroll
        for (int e = 0; e < 4; ++e)
          agg[e] = fmaf(cfe[e], win[e + cx], agg[e]);
      }
    }
    const float ctr[4] = {ac.x, ac.y, ac.z, ac.w};
    const float rfe[4] = {rf.x, rf.y, rf.z, rf.w};
    float oe[4];
#pragma unroll
    for (int e = 0; e < 4; ++e) {
      const float da = ctr[e] - rfe[e];
      oe[e] = agg[e] * __expf(-(da * da));   // exp(ALPHA*(nbr-ref)^2), ALPHA=-1
    }
    float4 o4;
    o4.x = oe[0]; o4.y = oe[1]; o4.z = oe[2]; o4.w = oe[3];
    *(float4*)(obase + (size_t)c * HW + x0) = o4;
  }
}

extern "C" void kernel_launch(void* const* d_in, const int* in_sizes, int n_in,
                              void* d_out, int out_size, void* d_ws, size_t ws_size,
                              hipStream_t stream) {
  const float* nbr = (const float*)d_in[0];
  const float* ref = (const float*)d_in[1];
  float*       out = (float*)d_out;
  fused_kernel<<<dim3(B * H), dim3(256), 0, stream>>>(nbr, ref, out);   // 512 row-blocks
}